// Round 9
// baseline (346.542 us; speedup 1.0000x reference)
//
#include <hip/hip_runtime.h>
#include <math.h>

// TreeMambaLayer: B=4, N=2048, D_MODEL=768, D_INNER=1536, DT_RANK=48
// Round 9: 13 -> 8 launches (sched+casts merged, xp_reduce fused into
// dt_gemm); MODE-1 epilogue repacked via LDS for coalesced uint4 stores.
// NOTE: SQ_LDS_BANK_CONFLICT == 4/ds_read_b128 is structural (R6==R7==R8).

#define ROWS 8192
#define DIN 1536
#define DMOD 768
#define NSEQ 2048
#define DTR 48
#define NSPLIT 8

typedef __bf16 bfrag __attribute__((ext_vector_type(8)));
typedef float f4 __attribute__((ext_vector_type(4)));

__device__ __forceinline__ unsigned short f2bf(float f) {
  unsigned int u = __float_as_uint(f);
  unsigned int r = (u + 0x7fffu + ((u >> 16) & 1u)) >> 16;
  return (unsigned short)r;
}
__device__ __forceinline__ float bf2f(unsigned short h) {
  return __uint_as_float(((unsigned int)h) << 16);
}

__device__ __forceinline__ void gld_lds16(const void* g, void* l) {
  __builtin_amdgcn_global_load_lds((const __attribute__((address_space(1))) void*)g,
                                   (__attribute__((address_space(3))) void*)l, 16, 0, 0);
}

// ------------------------------------------------------------- bf16 MFMA GEMM
// BK=32, 128x128 tile. MODE 0: fp32 C (scalar stores). MODE 1: XI bf16 +
// Z=silu bf16 with LDS-repacked coalesced uint4 stores.
template <int MODE>
__global__ __launch_bounds__(256) void mfma_gemm(
    const unsigned short* __restrict__ A, const unsigned short* __restrict__ Bt,
    void* __restrict__ C0v, void* __restrict__ C1v, int K, int ldc) {
  __shared__ unsigned short Sh[2 * 128 * 32];  // As | Bs ; reused as scratch
  unsigned short* As = Sh;
  unsigned short* Bs = Sh + 128 * 32;
  const int tid = threadIdx.x;
  const int w = tid >> 6, l = tid & 63;
  const int quad = l >> 4, l16 = l & 15;
  const int wrow = (w >> 1) * 64, wcol = (w & 1) * 64;
  const int row0 = blockIdx.y * 128, col0 = blockIdx.x * 128;

  f4 acc[4][4];
#pragma unroll
  for (int i = 0; i < 4; i++)
#pragma unroll
    for (int j = 0; j < 4; j++) acc[i][j] = (f4){0.f, 0.f, 0.f, 0.f};

  const int arow = row0 + w * 16 + (l >> 2);
  const int brow = col0 + w * 16 + (l >> 2);
  const int kcol = (((l & 3) ^ ((l >> 2) & 3)) * 8);  // swizzled chunk
  const int qs = (quad ^ (l16 & 3)) * 8;              // fragment chunk

  for (int k0 = 0; k0 < K; k0 += 32) {
#pragma unroll
    for (int r = 0; r < 2; r++) {
      gld_lds16(A + (size_t)(arow + r * 64) * K + k0 + kcol,
                (char*)As + r * 4096 + w * 1024);
      gld_lds16(Bt + (size_t)(brow + r * 64) * K + k0 + kcol,
                (char*)Bs + r * 4096 + w * 1024);
    }
    __syncthreads();
    bfrag af[4], bf[4];
#pragma unroll
    for (int i = 0; i < 4; i++)
      af[i] = *(const bfrag*)(const void*)(As + (wrow + i * 16 + l16) * 32 + qs);
#pragma unroll
    for (int j = 0; j < 4; j++)
      bf[j] = *(const bfrag*)(const void*)(Bs + (wcol + j * 16 + l16) * 32 + qs);
#pragma unroll
    for (int i = 0; i < 4; i++)
#pragma unroll
      for (int j = 0; j < 4; j++)
        acc[i][j] = __builtin_amdgcn_mfma_f32_16x16x32_bf16(af[i], bf[j], acc[i][j], 0, 0, 0);
    __syncthreads();
  }

  if (MODE == 0) {
    float* C0 = (float*)C0v;
    const int ccol = col0 + wcol + l16;
#pragma unroll
    for (int i = 0; i < 4; i++) {
      const int rb = row0 + wrow + i * 16 + quad * 4;
#pragma unroll
      for (int j = 0; j < 4; j++)
#pragma unroll
        for (int r = 0; r < 4; r++)
          C0[(size_t)(rb + r) * ldc + ccol + j * 16] = acc[i][j][r];
    }
  } else {
    const bool is_z = (col0 >= DIN);
    unsigned short* dst = is_z ? (unsigned short*)C1v : (unsigned short*)C0v;
    const int cb0 = col0 - (is_z ? DIN : 0);
    const int g = w >> 1;
    // repack via LDS: scratch 32 rows x 136 stride (16B-aligned rows)
    unsigned short* scratch = Sh;
#pragma unroll
    for (int i = 0; i < 4; i++) {
      __syncthreads();
#pragma unroll
      for (int j = 0; j < 4; j++)
#pragma unroll
        for (int r = 0; r < 4; r++) {
          float v = acc[i][j][r];
          if (is_z) v = v / (1.f + __expf(-v));
          scratch[(g * 16 + quad * 4 + r) * 136 + wcol + j * 16 + l16] = f2bf(v);
        }
      __syncthreads();
      const int sr = tid >> 3, cb = (tid & 7) * 16;
      const int grow = row0 + (sr >> 4) * 64 + i * 16 + (sr & 15);
      const uint4 v0 = *(const uint4*)&scratch[sr * 136 + cb];
      const uint4 v1 = *(const uint4*)&scratch[sr * 136 + cb + 8];
      *(uint4*)(dst + (size_t)grow * DIN + cb0 + cb) = v0;
      *(uint4*)(dst + (size_t)grow * DIN + cb0 + cb + 8) = v1;
    }
  }
}

// ------------------- prep1 (1024 thr): sched (block 0) + all flat casts
__global__ __launch_bounds__(1024) void prep1_kernel(
    const int* __restrict__ sidx, const int* __restrict__ spar,
    int* __restrict__ SLOT_NODE, int* __restrict__ SLOT_PNODE,
    int* __restrict__ LSTART, int* __restrict__ NLEV,
    const float* __restrict__ x, unsigned short* __restrict__ Xbf,
    const float* __restrict__ xpw, unsigned short* __restrict__ XPW,
    const float* __restrict__ dtw, unsigned short* __restrict__ DTWb,
    const float* __restrict__ A_log, float* __restrict__ negA) {
  const int bi = blockIdx.x;
  const int tid = threadIdx.x;
  if (bi == 0) {
    // ---- level schedule: Wyllie depth + histogram + scan + scatter
    __shared__ int par[2048], idx[2048], ancA[2048], ancB[2048], rnkA[2048], rnkB[2048];
    __shared__ int dmax;
    for (int i = tid; i < 2048; i += 1024) {
      const int p = spar[i];
      par[i] = p;
      idx[i] = sidx[i];
      ancA[i] = (p < 0) ? -1 : p;
      rnkA[i] = (p < 0) ? 0 : 1;
    }
    if (tid == 0) dmax = 0;
    __syncthreads();
    for (int r = 0; r < 11; r++) {
      int* ca = (r & 1) ? ancB : ancA;
      int* cr = (r & 1) ? rnkB : rnkA;
      int* na = (r & 1) ? ancA : ancB;
      int* nr = (r & 1) ? rnkA : rnkB;
      for (int i = tid; i < 2048; i += 1024) {
        const int a = ca[i], rv = cr[i];
        if (a >= 0) {
          nr[i] = rv + cr[a];
          na[i] = ca[a];
        } else {
          nr[i] = rv;
          na[i] = a;
        }
      }
      __syncthreads();
    }
    for (int i = tid; i < 2048; i += 1024) ancA[i] = 0;
    __syncthreads();
    for (int i = tid; i < 2048; i += 1024) {
      atomicAdd(&ancA[rnkB[i]], 1);
      atomicMax(&dmax, rnkB[i]);
    }
    __syncthreads();
    for (int s = 0; s < 11; s++) {
      const int off = 1 << s;
      int* cur = (s & 1) ? ancB : ancA;
      int* nxt = (s & 1) ? ancA : ancB;
      for (int i = tid; i < 2048; i += 1024) {
        int v = cur[i];
        if (i >= off) v += cur[i - off];
        nxt[i] = v;
      }
      __syncthreads();
    }
    for (int i = tid; i < 2049; i += 1024) {
      const int v = (i == 0) ? 0 : ancB[i - 1];
      LSTART[i] = v;
      if (i < 2048) rnkA[i] = v;
    }
    if (tid == 0) NLEV[0] = dmax + 1;
    __syncthreads();
    for (int i = tid; i < 2048; i += 1024) {
      const int d = rnkB[i];
      const int slot = atomicAdd(&rnkA[d], 1);
      SLOT_NODE[slot] = idx[i];
      const int p = par[i];
      SLOT_PNODE[slot] = (p < 0) ? -1 : idx[p];
    }
  } else if (bi < 1 + 1536) {
    // ---- x -> Xbf (8192x768, float4 vectorized)
    const int i = ((bi - 1) * 1024 + tid) * 4;
    const float4 v = *(const float4*)(x + i);
    union { unsigned short h[4]; uint2 u; } pk;
    pk.h[0] = f2bf(v.x);
    pk.h[1] = f2bf(v.y);
    pk.h[2] = f2bf(v.z);
    pk.h[3] = f2bf(v.w);
    *(uint2*)(Xbf + i) = pk.u;
  } else if (bi < 1 + 1536 + 96) {
    // ---- x_proj_w (1536x50) -> XPW (64x1536), cols>=50 zero
    const int i = (bi - 1537) * 1024 + tid;  // 64*1536
    const int c = i / 1536, k = i % 1536;
    XPW[i] = (c < 50) ? f2bf(xpw[(size_t)k * 50 + c]) : (unsigned short)0;
  } else if (bi < 1 + 1536 + 96 + 96) {
    // ---- dt_proj_w (48x1536) -> DTWb (1536x64), k>=48 zero
    const int i = (bi - 1633) * 1024 + tid;  // 1536*64
    const int d = i >> 6, k = i & 63;
    DTWb[i] = (k < 48) ? f2bf(dtw[(size_t)k * DIN + d]) : (unsigned short)0;
  } else {
    // ---- negA
    const int i = (bi - 1729) * 1024 + tid;
    if (i < DIN) negA[i] = -__expf(A_log[i]);
  }
}

// ------------------- prep2 (256 thr): both weight transposes, fp32 -> bf16^T
__global__ __launch_bounds__(256) void prep2_kernel(
    const float* __restrict__ W1, unsigned short* __restrict__ W1t,
    const float* __restrict__ W2, unsigned short* __restrict__ W2t) {
  __shared__ float t[32][33];
  int idx = blockIdx.x;
  const float* W;
  unsigned short* Wt;
  int K, N, n0, k0;
  if (idx < 2304) {  // in_proj: K=768, N=3072 -> 96x24 tiles
    W = W1; Wt = W1t; K = DMOD; N = 2 * DIN;
    n0 = (idx % 96) * 32; k0 = (idx / 96) * 32;
  } else {           // out_proj: K=1536, N=768 -> 24x48 tiles
    idx -= 2304;
    W = W2; Wt = W2t; K = DIN; N = DMOD;
    n0 = (idx % 24) * 32; k0 = (idx / 24) * 32;
  }
  const int tx = threadIdx.x & 31, ty = threadIdx.x >> 5;
  for (int i = ty; i < 32; i += 8) t[i][tx] = W[(size_t)(k0 + i) * N + n0 + tx];
  __syncthreads();
  for (int i = ty; i < 32; i += 8)
    Wt[(size_t)(n0 + i) * K + k0 + tx] = f2bf(t[tx][i]);
}

// ------------------------------------------------- x_dbl: split-K bf16 MFMA
__global__ __launch_bounds__(256) void xdbl_mfma(
    const unsigned short* __restrict__ XI, const unsigned short* __restrict__ XPW,
    float* __restrict__ XP) {
  __shared__ unsigned short As[128 * 32];
  __shared__ unsigned short Bs[64 * 32];
  const int tid = threadIdx.x;
  const int w = tid >> 6, l = tid & 63;
  const int quad = l >> 4, l16 = l & 15;
  const int split = blockIdx.x;
  const int row0 = blockIdx.y * 128;
  const int kbase = split * (DIN / NSPLIT);  // 192

  f4 acc[2][4];
#pragma unroll
  for (int i = 0; i < 2; i++)
#pragma unroll
    for (int j = 0; j < 4; j++) acc[i][j] = (f4){0.f, 0.f, 0.f, 0.f};

  const int srow = w * 16 + (l >> 2);
  const int kcol = (((l & 3) ^ ((l >> 2) & 3)) * 8);
  const int qs = (quad ^ (l16 & 3)) * 8;

  for (int c = 0; c < 6; c++) {
    const int k0 = kbase + c * 32;
#pragma unroll
    for (int r = 0; r < 2; r++) {
      gld_lds16(XI + (size_t)(row0 + srow + r * 64) * DIN + k0 + kcol,
                (char*)As + r * 4096 + w * 1024);
    }
    gld_lds16(XPW + (size_t)srow * DIN + k0 + kcol, (char*)Bs + w * 1024);
    __syncthreads();
    bfrag af[2], bf[4];
#pragma unroll
    for (int i = 0; i < 2; i++)
      af[i] = *(const bfrag*)(const void*)(As + (w * 32 + i * 16 + l16) * 32 + qs);
#pragma unroll
    for (int j = 0; j < 4; j++)
      bf[j] = *(const bfrag*)(const void*)(Bs + (j * 16 + l16) * 32 + qs);
#pragma unroll
    for (int i = 0; i < 2; i++)
#pragma unroll
      for (int j = 0; j < 4; j++)
        acc[i][j] = __builtin_amdgcn_mfma_f32_16x16x32_bf16(af[i], bf[j], acc[i][j], 0, 0, 0);
    __syncthreads();
  }

  float* dst = XP + (size_t)split * ROWS * 64 + (size_t)row0 * 64;
#pragma unroll
  for (int i = 0; i < 2; i++) {
    const int rb = w * 32 + i * 16 + quad * 4;
#pragma unroll
    for (int j = 0; j < 4; j++) {
      const int col = j * 16 + l16;
#pragma unroll
      for (int r = 0; r < 4; r++) dst[(size_t)(rb + r) * 64 + col] = acc[i][j][r];
    }
  }
}

// ------------- dt GEMM (K=64) with fused XP-reduction; -> DT bf16 + BC/CC
// grid (12, 128). 64 rows x 128 cols per block. A reduced in-block (no swizzle),
// B staged via gld_lds16 (swizzled).
__global__ __launch_bounds__(256) void dt_gemm(
    const float* __restrict__ XP, const unsigned short* __restrict__ DTWb,
    const float* __restrict__ bias, float* __restrict__ BCv,
    float* __restrict__ CCv, unsigned short* __restrict__ DT) {
  __shared__ unsigned short As[2][64 * 32];
  __shared__ unsigned short Bs[2][128 * 32];
  const int tid = threadIdx.x;
  const int w = tid >> 6, l = tid & 63;
  const int quad = l >> 4, l16 = l & 15;
  const int wrow = (w >> 1) * 32, wcol = (w & 1) * 64;
  const int row0 = blockIdx.y * 64, col0 = blockIdx.x * 128;
  const int srow = w * 16 + (l >> 2);
  const int koff = (((l & 3) ^ ((l >> 2) & 3)) * 8);
  const int qs_b = (quad ^ (l16 & 3)) * 8;

#pragma unroll
  for (int c = 0; c < 2; c++)
#pragma unroll
    for (int r = 0; r < 2; r++)
      gld_lds16(DTWb + (size_t)(col0 + srow + r * 64) * 64 + c * 32 + koff,
                (char*)Bs[c] + r * 4096 + w * 1024);

  // fused xp_reduce: 64 rows x 64 cols -> As (bf16); block.x==0 emits BC/CC
#pragma unroll
  for (int it = 0; it < 16; it++) {
    const int e = tid + it * 256;
    const int rr = e >> 6, cc = e & 63;
    const float* pp = XP + (size_t)(row0 + rr) * 64 + cc;
    float s = 0.f;
#pragma unroll
    for (int sp = 0; sp < NSPLIT; sp++) s += pp[(size_t)sp * ROWS * 64];
    As[cc >> 5][rr * 32 + (cc & 31)] = f2bf(s);
    if (blockIdx.x == 0) {
      if (cc == 48) BCv[row0 + rr] = s;
      else if (cc == 49) CCv[row0 + rr] = s;
    }
  }
  __syncthreads();

  f4 acc[2][4];
#pragma unroll
  for (int i = 0; i < 2; i++)
#pragma unroll
    for (int j = 0; j < 4; j++) acc[i][j] = (f4){0.f, 0.f, 0.f, 0.f};

#pragma unroll
  for (int c = 0; c < 2; c++) {
    bfrag af[2], bf[4];
#pragma unroll
    for (int i = 0; i < 2; i++)
      af[i] = *(const bfrag*)(const void*)(As[c] + (wrow + i * 16 + l16) * 32 + quad * 8);
#pragma unroll
    for (int j = 0; j < 4; j++)
      bf[j] = *(const bfrag*)(const void*)(Bs[c] + (wcol + j * 16 + l16) * 32 + qs_b);
#pragma unroll
    for (int i = 0; i < 2; i++)
#pragma unroll
      for (int j = 0; j < 4; j++)
        acc[i][j] = __builtin_amdgcn_mfma_f32_16x16x32_bf16(af[i], bf[j], acc[i][j], 0, 0, 0);
  }

  float bj[4];
#pragma unroll
  for (int j = 0; j < 4; j++) bj[j] = bias[col0 + wcol + j * 16 + l16];
#pragma unroll
  for (int i = 0; i < 2; i++) {
#pragma unroll
    for (int r = 0; r < 4; r++) {
      const int row = row0 + wrow + i * 16 + quad * 4 + r;
#pragma unroll
      for (int j = 0; j < 4; j++) {
        const int d = col0 + wcol + j * 16 + l16;
        const float s = acc[i][j][r] + bj[j];
        const float sp = fmaxf(s, 0.f) + __logf(1.f + __expf(-fabsf(s)));
        DT[(size_t)row * DIN + d] = f2bf(sp);
      }
    }
  }
}

// ------------------------------------ tree recurrence (dA/dBx fused, h bf16)
__global__ __launch_bounds__(256) void recur_kernel(
    const unsigned short* __restrict__ DT, const unsigned short* __restrict__ XI,
    const float* __restrict__ negA, const float* __restrict__ BCv,
    unsigned short* __restrict__ Hb,
    const int* __restrict__ SLOT_NODE, const int* __restrict__ SLOT_PNODE,
    const int* __restrict__ LSTART, const int* __restrict__ NLEV) {
  const int tid = threadIdx.x;
  const int base_c8 = blockIdx.x * 2;  // 768 chunks of 8 bf16 (192/batch x 4)
  const int nlev = NLEV[0];
  for (int L = 0; L < nlev; L++) {
    const int s0 = LSTART[L], s1 = LSTART[L + 1];
    const int items = (s1 - s0) * 2;
    for (int it = tid; it < items; it += 256) {
      const int s = s0 + (it >> 1);
      const int c8 = base_c8 + (it & 1);
      const int node = SLOT_NODE[s];
      const int pn = SLOT_PNODE[s];
      const int b = c8 / 192, d8 = c8 % 192;
      const size_t row = (size_t)b * NSEQ + node;
      const size_t off = row * DIN + d8 * 8;
      union { uint4 u; unsigned short h[8]; } dtu, xiu, hpu, hvu;
      dtu.u = *(const uint4*)(DT + off);
      xiu.u = *(const uint4*)(XI + off);
      const float4 a0 = *(const float4*)(negA + d8 * 8);
      const float4 a1 = *(const float4*)(negA + d8 * 8 + 4);
      const float bc = BCv[row];
      float hp[8];
      if (pn >= 0) {
        hpu.u = *(const uint4*)(Hb + ((size_t)b * NSEQ + pn) * DIN + d8 * 8);
#pragma unroll
        for (int e = 0; e < 8; e++) hp[e] = bf2f(hpu.h[e]);
      } else {
#pragma unroll
        for (int e = 0; e < 8; e++) hp[e] = 0.f;
      }
      const float an[8] = {a0.x, a0.y, a0.z, a0.w, a1.x, a1.y, a1.z, a1.w};
#pragma unroll
      for (int e = 0; e < 8; e++) {
        const float t = bf2f(dtu.h[e]);
        const float hv = fmaf(__expf(t * an[e]), hp[e], t * bc * bf2f(xiu.h[e]));
        hvu.h[e] = f2bf(hv);
      }
      *(uint4*)(Hb + off) = hvu.u;
    }
    __syncthreads();
  }
}

// --------------------------------------------- y, layernorm, z-gate -> bf16
__global__ __launch_bounds__(256) void ln_kernel(
    const unsigned short* __restrict__ Hb, const float* __restrict__ CCv,
    const unsigned short* __restrict__ XI, const float* __restrict__ Dp,
    const float* __restrict__ gamma, const float* __restrict__ beta,
    const unsigned short* __restrict__ Z, unsigned short* __restrict__ YLN) {
  const int row = blockIdx.x;
  const int tid = threadIdx.x;
  const float C = CCv[row];
  const unsigned short* hrow = Hb + (size_t)row * DIN;
  const unsigned short* xrow = XI + (size_t)row * DIN;
  float y[6];
  float s = 0.f, s2 = 0.f;
#pragma unroll
  for (int i = 0; i < 6; i++) {
    const int d = tid + i * 256;
    const float v = fmaf(bf2f(hrow[d]), C, Dp[d] * bf2f(xrow[d]));
    y[i] = v;
    s += v;
    s2 = fmaf(v, v, s2);
  }
#pragma unroll
  for (int off = 32; off >= 1; off >>= 1) {
    s += __shfl_down(s, off);
    s2 += __shfl_down(s2, off);
  }
  __shared__ float rs[4], rs2[4];
  const int w = tid >> 6;
  if ((tid & 63) == 0) {
    rs[w] = s;
    rs2[w] = s2;
  }
  __syncthreads();
  const float ts = rs[0] + rs[1] + rs[2] + rs[3];
  const float ts2 = rs2[0] + rs2[1] + rs2[2] + rs2[3];
  const float mu = ts * (1.f / 1536.f);
  const float var = ts2 * (1.f / 1536.f) - mu * mu;
  const float inv = rsqrtf(var + 1e-5f);
  unsigned short* yrow = YLN + (size_t)row * DIN;
  const unsigned short* zrow = Z + (size_t)row * DIN;
#pragma unroll
  for (int i = 0; i < 6; i++) {
    const int d = tid + i * 256;
    const float o = (y[i] - mu) * inv * gamma[d] + beta[d];
    yrow[d] = f2bf(o * bf2f(zrow[d]));
  }
}

// ---------------------------------------------------------------------- launch
extern "C" void kernel_launch(void* const* d_in, const int* in_sizes, int n_in,
                              void* d_out, int out_size, void* d_ws, size_t ws_size,
                              hipStream_t stream) {
  const float* x = (const float*)d_in[0];
  const int* sidx = (const int*)d_in[1];
  const int* spar = (const int*)d_in[2];
  const float* in_proj = (const float*)d_in[3];
  const float* x_proj = (const float*)d_in[4];
  const float* dt_proj = (const float*)d_in[5];
  const float* dt_b = (const float*)d_in[6];
  const float* A_log = (const float*)d_in[7];
  const float* Dp = (const float*)d_in[8];
  const float* gamma = (const float*)d_in[9];
  const float* beta = (const float*)d_in[10];
  const float* out_proj = (const float*)d_in[11];
  float* out = (float*)d_out;

  char* p = (char*)d_ws;
  const size_t RC = (size_t)ROWS * DIN;
  unsigned short* XI = (unsigned short*)p;  p += RC * 2;               // 25.2 MB
  unsigned short* Z = (unsigned short*)p;   p += RC * 2;               // 25.2 MB
  unsigned short* DT = (unsigned short*)p;  p += RC * 2;               // 25.2 MB
  unsigned short* Hb = (unsigned short*)p;  p += RC * 2;               // 25.2 MB
  float* XP = (float*)p;                    p += (size_t)NSPLIT * ROWS * 64 * 4;  // 16.8 MB
  float* BCv = (float*)p;                   p += ROWS * 4;
  float* CCv = (float*)p;                   p += ROWS * 4;
  float* negA = (float*)p;                  p += DIN * 4;
  unsigned short* Xbf = (unsigned short*)p; p += (size_t)ROWS * DMOD * 2;        // 12.6 MB
  unsigned short* W1t = (unsigned short*)p; p += (size_t)2 * DIN * DMOD * 2;     // 4.7 MB
  unsigned short* W2t = (unsigned short*)p; p += (size_t)DMOD * DIN * 2;         // 2.4 MB
  unsigned short* XPW = (unsigned short*)p; p += (size_t)64 * DIN * 2;
  unsigned short* DTWb = (unsigned short*)p; p += (size_t)DIN * 64 * 2;
  int* ipart = (int*)p;
  int* SLOT_NODE = ipart;
  int* SLOT_PNODE = ipart + 2048;
  int* LSTART = ipart + 4096;
  int* NLEV = ipart + 4096 + 2049;
  unsigned short* YLN = DT;  // DT dead after recur; reuse for LN output (bf16)

  prep1_kernel<<<1731, 1024, 0, stream>>>(sidx, spar, SLOT_NODE, SLOT_PNODE,
                                          LSTART, NLEV, x, Xbf, x_proj, XPW,
                                          dt_proj, DTWb, A_log, negA);
  prep2_kernel<<<3456, 256, 0, stream>>>(in_proj, W1t, out_proj, W2t);
  mfma_gemm<1><<<dim3(24, 64), 256, 0, stream>>>(Xbf, W1t, XI, Z, DMOD, DIN);
  xdbl_mfma<<<dim3(NSPLIT, 64), 256, 0, stream>>>(XI, XPW, XP);
  dt_gemm<<<dim3(12, 128), 256, 0, stream>>>(XP, DTWb, dt_b, BCv, CCv, DT);
  recur_kernel<<<384, 256, 0, stream>>>(DT, XI, negA, BCv, Hb, SLOT_NODE, SLOT_PNODE, LSTART, NLEV);
  ln_kernel<<<ROWS, 256, 0, stream>>>(Hb, CCv, XI, Dp, gamma, beta, Z, YLN);
  mfma_gemm<0><<<dim3(6, 64), 256, 0, stream>>>(YLN, W2t, out, nullptr, DIN, DMOD);
}

// Round 10
// 324.156 us; speedup vs baseline: 1.0691x; 1.0691x over previous
//
#include <hip/hip_runtime.h>
#include <math.h>

// TreeMambaLayer: B=4, N=2048, D_MODEL=768, D_INNER=1536, DT_RANK=48
// Round 10: recur -> LDS-resident h (64KB/block, 2 blocks/CU) with dA/dBx
// precomputed bf16 in slot-permuted row order (coalesced, address-independent
// level loads). Revert R9's XP re-read fusion + epilogue repack.

#define ROWS 8192
#define DIN 1536
#define DMOD 768
#define NSEQ 2048
#define DTR 48
#define NSPLIT 8

typedef __bf16 bfrag __attribute__((ext_vector_type(8)));
typedef float f4 __attribute__((ext_vector_type(4)));

__device__ __forceinline__ unsigned short f2bf(float f) {
  unsigned int u = __float_as_uint(f);
  unsigned int r = (u + 0x7fffu + ((u >> 16) & 1u)) >> 16;
  return (unsigned short)r;
}
__device__ __forceinline__ float bf2f(unsigned short h) {
  return __uint_as_float(((unsigned int)h) << 16);
}

__device__ __forceinline__ void gld_lds16(const void* g, void* l) {
  __builtin_amdgcn_global_load_lds((const __attribute__((address_space(1))) void*)g,
                                   (__attribute__((address_space(3))) void*)l, 16, 0, 0);
}

// ------------------------------------------------------------- bf16 MFMA GEMM
// BK=32, 128x128 tile, swizzled LDS. MODE 0: fp32 C. MODE 1: XI bf16 + Z silu.
template <int MODE>
__global__ __launch_bounds__(256) void mfma_gemm(
    const unsigned short* __restrict__ A, const unsigned short* __restrict__ Bt,
    void* __restrict__ C0v, void* __restrict__ C1v, int K, int ldc) {
  __shared__ unsigned short As[128 * 32];
  __shared__ unsigned short Bs[128 * 32];
  const int tid = threadIdx.x;
  const int w = tid >> 6, l = tid & 63;
  const int quad = l >> 4, l16 = l & 15;
  const int wrow = (w >> 1) * 64, wcol = (w & 1) * 64;
  const int row0 = blockIdx.y * 128, col0 = blockIdx.x * 128;

  f4 acc[4][4];
#pragma unroll
  for (int i = 0; i < 4; i++)
#pragma unroll
    for (int j = 0; j < 4; j++) acc[i][j] = (f4){0.f, 0.f, 0.f, 0.f};

  const int arow = row0 + w * 16 + (l >> 2);
  const int brow = col0 + w * 16 + (l >> 2);
  const int kcol = (((l & 3) ^ ((l >> 2) & 3)) * 8);  // swizzled chunk
  const int qs = (quad ^ (l16 & 3)) * 8;              // fragment chunk

  for (int k0 = 0; k0 < K; k0 += 32) {
#pragma unroll
    for (int r = 0; r < 2; r++) {
      gld_lds16(A + (size_t)(arow + r * 64) * K + k0 + kcol,
                (char*)As + r * 4096 + w * 1024);
      gld_lds16(Bt + (size_t)(brow + r * 64) * K + k0 + kcol,
                (char*)Bs + r * 4096 + w * 1024);
    }
    __syncthreads();
    bfrag af[4], bf[4];
#pragma unroll
    for (int i = 0; i < 4; i++)
      af[i] = *(const bfrag*)(const void*)(As + (wrow + i * 16 + l16) * 32 + qs);
#pragma unroll
    for (int j = 0; j < 4; j++)
      bf[j] = *(const bfrag*)(const void*)(Bs + (wcol + j * 16 + l16) * 32 + qs);
#pragma unroll
    for (int i = 0; i < 4; i++)
#pragma unroll
      for (int j = 0; j < 4; j++)
        acc[i][j] = __builtin_amdgcn_mfma_f32_16x16x32_bf16(af[i], bf[j], acc[i][j], 0, 0, 0);
    __syncthreads();
  }

  if (MODE == 0) {
    float* C0 = (float*)C0v;
    const int ccol = col0 + wcol + l16;
#pragma unroll
    for (int i = 0; i < 4; i++) {
      const int rb = row0 + wrow + i * 16 + quad * 4;
#pragma unroll
      for (int j = 0; j < 4; j++)
#pragma unroll
        for (int r = 0; r < 4; r++)
          C0[(size_t)(rb + r) * ldc + ccol + j * 16] = acc[i][j][r];
    }
  } else {
    const bool is_z = (col0 >= DIN);
    unsigned short* dst = is_z ? (unsigned short*)C1v : (unsigned short*)C0v;
    const int cbase = col0 + wcol + l16 - (is_z ? DIN : 0);
#pragma unroll
    for (int i = 0; i < 4; i++) {
      const int rb = row0 + wrow + i * 16 + quad * 4;
#pragma unroll
      for (int j = 0; j < 4; j++)
#pragma unroll
        for (int r = 0; r < 4; r++) {
          float v = acc[i][j][r];
          if (is_z) v = v / (1.f + __expf(-v));
          dst[(size_t)(rb + r) * DIN + cbase + j * 16] = f2bf(v);
        }
    }
  }
}

// ------------------- prep1 (1024 thr): sched (block 0) + all flat casts
// SLOT_PACK[slot] = node | ((pnode+1)<<12); SLOTINV[node] = slot.
__global__ __launch_bounds__(1024) void prep1_kernel(
    const int* __restrict__ sidx, const int* __restrict__ spar,
    int* __restrict__ SLOT_PACK, int* __restrict__ SLOTINV,
    int* __restrict__ LSTART, int* __restrict__ NLEV,
    const float* __restrict__ x, unsigned short* __restrict__ Xbf,
    const float* __restrict__ xpw, unsigned short* __restrict__ XPW,
    const float* __restrict__ dtw, unsigned short* __restrict__ DTWb,
    const float* __restrict__ A_log, float* __restrict__ negA) {
  const int bi = blockIdx.x;
  const int tid = threadIdx.x;
  if (bi == 0) {
    __shared__ int par[2048], idx[2048], ancA[2048], ancB[2048], rnkA[2048], rnkB[2048];
    __shared__ int dmax;
    for (int i = tid; i < 2048; i += 1024) {
      const int p = spar[i];
      par[i] = p;
      idx[i] = sidx[i];
      ancA[i] = (p < 0) ? -1 : p;
      rnkA[i] = (p < 0) ? 0 : 1;
    }
    if (tid == 0) dmax = 0;
    __syncthreads();
    for (int r = 0; r < 11; r++) {
      int* ca = (r & 1) ? ancB : ancA;
      int* cr = (r & 1) ? rnkB : rnkA;
      int* na = (r & 1) ? ancA : ancB;
      int* nr = (r & 1) ? rnkA : rnkB;
      for (int i = tid; i < 2048; i += 1024) {
        const int a = ca[i], rv = cr[i];
        if (a >= 0) {
          nr[i] = rv + cr[a];
          na[i] = ca[a];
        } else {
          nr[i] = rv;
          na[i] = a;
        }
      }
      __syncthreads();
    }
    for (int i = tid; i < 2048; i += 1024) ancA[i] = 0;
    __syncthreads();
    for (int i = tid; i < 2048; i += 1024) {
      atomicAdd(&ancA[rnkB[i]], 1);
      atomicMax(&dmax, rnkB[i]);
    }
    __syncthreads();
    for (int s = 0; s < 11; s++) {
      const int off = 1 << s;
      int* cur = (s & 1) ? ancB : ancA;
      int* nxt = (s & 1) ? ancA : ancB;
      for (int i = tid; i < 2048; i += 1024) {
        int v = cur[i];
        if (i >= off) v += cur[i - off];
        nxt[i] = v;
      }
      __syncthreads();
    }
    for (int i = tid; i < 2049; i += 1024) {
      const int v = (i == 0) ? 0 : ancB[i - 1];
      LSTART[i] = v;
      if (i < 2048) rnkA[i] = v;
    }
    if (tid == 0) NLEV[0] = dmax + 1;
    __syncthreads();
    for (int i = tid; i < 2048; i += 1024) {
      const int d = rnkB[i];
      const int slot = atomicAdd(&rnkA[d], 1);
      const int node = idx[i];
      const int p = par[i];
      const int pn = (p < 0) ? -1 : idx[p];
      SLOT_PACK[slot] = node | ((pn + 1) << 12);
      SLOTINV[node] = slot;
    }
  } else if (bi < 1 + 1536) {
    const int i = ((bi - 1) * 1024 + tid) * 4;
    const float4 v = *(const float4*)(x + i);
    union { unsigned short h[4]; uint2 u; } pk;
    pk.h[0] = f2bf(v.x);
    pk.h[1] = f2bf(v.y);
    pk.h[2] = f2bf(v.z);
    pk.h[3] = f2bf(v.w);
    *(uint2*)(Xbf + i) = pk.u;
  } else if (bi < 1 + 1536 + 96) {
    const int i = (bi - 1537) * 1024 + tid;  // 64*1536
    const int c = i / 1536, k = i % 1536;
    XPW[i] = (c < 50) ? f2bf(xpw[(size_t)k * 50 + c]) : (unsigned short)0;
  } else if (bi < 1 + 1536 + 96 + 96) {
    const int i = (bi - 1633) * 1024 + tid;  // 1536*64
    const int d = i >> 6, k = i & 63;
    DTWb[i] = (k < 48) ? f2bf(dtw[(size_t)k * DIN + d]) : (unsigned short)0;
  } else {
    const int i = (bi - 1729) * 1024 + tid;
    if (i < DIN) negA[i] = -__expf(A_log[i]);
  }
}

// ------------------- prep2 (256 thr): both weight transposes, fp32 -> bf16^T
__global__ __launch_bounds__(256) void prep2_kernel(
    const float* __restrict__ W1, unsigned short* __restrict__ W1t,
    const float* __restrict__ W2, unsigned short* __restrict__ W2t) {
  __shared__ float t[32][33];
  int idx = blockIdx.x;
  const float* W;
  unsigned short* Wt;
  int K, N, n0, k0;
  if (idx < 2304) {  // in_proj: K=768, N=3072 -> 96x24 tiles
    W = W1; Wt = W1t; K = DMOD; N = 2 * DIN;
    n0 = (idx % 96) * 32; k0 = (idx / 96) * 32;
  } else {           // out_proj: K=1536, N=768 -> 24x48 tiles
    idx -= 2304;
    W = W2; Wt = W2t; K = DIN; N = DMOD;
    n0 = (idx % 24) * 32; k0 = (idx / 24) * 32;
  }
  const int tx = threadIdx.x & 31, ty = threadIdx.x >> 5;
  for (int i = ty; i < 32; i += 8) t[i][tx] = W[(size_t)(k0 + i) * N + n0 + tx];
  __syncthreads();
  for (int i = ty; i < 32; i += 8)
    Wt[(size_t)(n0 + i) * K + k0 + tx] = f2bf(t[tx][i]);
}

// ------------------------------------------------- x_dbl: split-K bf16 MFMA
__global__ __launch_bounds__(256) void xdbl_mfma(
    const unsigned short* __restrict__ XI, const unsigned short* __restrict__ XPW,
    float* __restrict__ XP) {
  __shared__ unsigned short As[128 * 32];
  __shared__ unsigned short Bs[64 * 32];
  const int tid = threadIdx.x;
  const int w = tid >> 6, l = tid & 63;
  const int quad = l >> 4, l16 = l & 15;
  const int split = blockIdx.x;
  const int row0 = blockIdx.y * 128;
  const int kbase = split * (DIN / NSPLIT);  // 192

  f4 acc[2][4];
#pragma unroll
  for (int i = 0; i < 2; i++)
#pragma unroll
    for (int j = 0; j < 4; j++) acc[i][j] = (f4){0.f, 0.f, 0.f, 0.f};

  const int srow = w * 16 + (l >> 2);
  const int kcol = (((l & 3) ^ ((l >> 2) & 3)) * 8);
  const int qs = (quad ^ (l16 & 3)) * 8;

  for (int c = 0; c < 6; c++) {
    const int k0 = kbase + c * 32;
#pragma unroll
    for (int r = 0; r < 2; r++) {
      gld_lds16(XI + (size_t)(row0 + srow + r * 64) * DIN + k0 + kcol,
                (char*)As + r * 4096 + w * 1024);
    }
    gld_lds16(XPW + (size_t)srow * DIN + k0 + kcol, (char*)Bs + w * 1024);
    __syncthreads();
    bfrag af[2], bf[4];
#pragma unroll
    for (int i = 0; i < 2; i++)
      af[i] = *(const bfrag*)(const void*)(As + (w * 32 + i * 16 + l16) * 32 + qs);
#pragma unroll
    for (int j = 0; j < 4; j++)
      bf[j] = *(const bfrag*)(const void*)(Bs + (j * 16 + l16) * 32 + qs);
#pragma unroll
    for (int i = 0; i < 2; i++)
#pragma unroll
      for (int j = 0; j < 4; j++)
        acc[i][j] = __builtin_amdgcn_mfma_f32_16x16x32_bf16(af[i], bf[j], acc[i][j], 0, 0, 0);
    __syncthreads();
  }

  float* dst = XP + (size_t)split * ROWS * 64 + (size_t)row0 * 64;
#pragma unroll
  for (int i = 0; i < 2; i++) {
    const int rb = w * 32 + i * 16 + quad * 4;
#pragma unroll
    for (int j = 0; j < 4; j++) {
      const int col = j * 16 + l16;
#pragma unroll
      for (int r = 0; r < 4; r++) dst[(size_t)(rb + r) * 64 + col] = acc[i][j][r];
    }
  }
}

// -------------------------- reduce XP partials -> DTLRb bf16 + BC/CC fp32
__global__ __launch_bounds__(256) void xp_reduce(
    const float* __restrict__ XP, unsigned short* __restrict__ DTLRb,
    float* __restrict__ BCv, float* __restrict__ CCv) {
  const int i = blockIdx.x * 256 + threadIdx.x;  // 8192*16
  const int row = i >> 4, c4 = (i & 15) * 4;
  const float* p = XP + (size_t)row * 64 + c4;
  float4 s = make_float4(0.f, 0.f, 0.f, 0.f);
#pragma unroll
  for (int sp = 0; sp < NSPLIT; sp++) {
    const float4 v = *(const float4*)(p + (size_t)sp * ROWS * 64);
    s.x += v.x;
    s.y += v.y;
    s.z += v.z;
    s.w += v.w;
  }
  if (c4 == 48) {
    BCv[row] = s.x;
    CCv[row] = s.y;
  }
  union { unsigned short h[4]; uint2 u; } pk;
  pk.h[0] = f2bf(s.x);
  pk.h[1] = f2bf(s.y);
  pk.h[2] = f2bf(s.z);
  pk.h[3] = f2bf(s.w);
  *(uint2*)(DTLRb + (size_t)row * 64 + c4) = pk.u;
}

// ------- dt GEMM (K=64) -> dA/dBx bf16, rows permuted to slot order.
// grid (12, 128). 64 rows x 128 cols per block.
__global__ __launch_bounds__(256) void dt_gemm(
    const unsigned short* __restrict__ DTLRb, const unsigned short* __restrict__ DTWb,
    const float* __restrict__ bias, const float* __restrict__ negA,
    const float* __restrict__ BCv, const unsigned short* __restrict__ XI,
    const int* __restrict__ SLOTINV,
    unsigned short* __restrict__ DAp, unsigned short* __restrict__ DBXp) {
  __shared__ unsigned short As[2][64 * 32];
  __shared__ unsigned short Bs[2][128 * 32];
  __shared__ int sinv[64];
  __shared__ float bcs[64];
  const int tid = threadIdx.x;
  const int w = tid >> 6, l = tid & 63;
  const int quad = l >> 4, l16 = l & 15;
  const int wrow = (w >> 1) * 32, wcol = (w & 1) * 64;
  const int row0 = blockIdx.y * 64, col0 = blockIdx.x * 128;
  const int p0 = row0 & (NSEQ - 1);       // position base (batch-local)
  const int bbase = row0 & ~(NSEQ - 1);   // b*2048
  const int srow = w * 16 + (l >> 2);
  const int koff = (((l & 3) ^ ((l >> 2) & 3)) * 8);
  const int qs = (quad ^ (l16 & 3)) * 8;

#pragma unroll
  for (int c = 0; c < 2; c++) {
    gld_lds16(DTLRb + (size_t)(row0 + srow) * 64 + c * 32 + koff,
              (char*)As[c] + w * 1024);
#pragma unroll
    for (int r = 0; r < 2; r++)
      gld_lds16(DTWb + (size_t)(col0 + srow + r * 64) * 64 + c * 32 + koff,
                (char*)Bs[c] + r * 4096 + w * 1024);
  }
  if (tid < 64) {
    sinv[tid] = SLOTINV[p0 + tid];
    bcs[tid] = BCv[row0 + tid];
  }
  __syncthreads();

  f4 acc[2][4];
#pragma unroll
  for (int i = 0; i < 2; i++)
#pragma unroll
    for (int j = 0; j < 4; j++) acc[i][j] = (f4){0.f, 0.f, 0.f, 0.f};

#pragma unroll
  for (int c = 0; c < 2; c++) {
    bfrag af[2], bf[4];
#pragma unroll
    for (int i = 0; i < 2; i++)
      af[i] = *(const bfrag*)(const void*)(As[c] + (wrow + i * 16 + l16) * 32 + qs);
#pragma unroll
    for (int j = 0; j < 4; j++)
      bf[j] = *(const bfrag*)(const void*)(Bs[c] + (wcol + j * 16 + l16) * 32 + qs);
#pragma unroll
    for (int i = 0; i < 2; i++)
#pragma unroll
      for (int j = 0; j < 4; j++)
        acc[i][j] = __builtin_amdgcn_mfma_f32_16x16x32_bf16(af[i], bf[j], acc[i][j], 0, 0, 0);
  }

  float bj[4], aj[4];
#pragma unroll
  for (int j = 0; j < 4; j++) {
    const int d = col0 + wcol + j * 16 + l16;
    bj[j] = bias[d];
    aj[j] = negA[d];
  }
#pragma unroll
  for (int i = 0; i < 2; i++) {
#pragma unroll
    for (int r = 0; r < 4; r++) {
      const int row_l = wrow + i * 16 + quad * 4 + r;
      const int row = row0 + row_l;
      const float bc = bcs[row_l];
      const size_t rp = (size_t)(bbase + sinv[row_l]) * DIN;
#pragma unroll
      for (int j = 0; j < 4; j++) {
        const int d = col0 + wcol + j * 16 + l16;
        const float s = acc[i][j][r] + bj[j];
        const float sp = fmaxf(s, 0.f) + __logf(1.f + __expf(-fabsf(s)));
        const float xi = bf2f(XI[(size_t)row * DIN + d]);
        DAp[rp + d] = f2bf(__expf(sp * aj[j]));
        DBXp[rp + d] = f2bf(sp * bc * xi);
      }
    }
  }
}

// ----------------- tree recurrence: h resident in LDS, slot-ordered loads
// block owns 16 bf16 columns (2 chunks of 8); h[node][16] in LDS (64KB).
__global__ __launch_bounds__(256) void recur_kernel(
    const unsigned short* __restrict__ DAp, const unsigned short* __restrict__ DBXp,
    unsigned short* __restrict__ Hb,
    const int* __restrict__ SLOT_PACK, const int* __restrict__ LSTART,
    const int* __restrict__ NLEV) {
  __shared__ unsigned short hl[NSEQ * 16];  // 64 KB
  __shared__ int spack[NSEQ];               // 8 KB
  __shared__ int lst[258];                  // ~1 KB
  const int tid = threadIdx.x;
  const int c8a = blockIdx.x * 2;           // both chunks in same batch
  const int b = c8a / 192;
  const int d8a = c8a % 192;
  const int nlev = NLEV[0];
  for (int i = tid; i < NSEQ; i += 256) spack[i] = SLOT_PACK[i];
  const int nl = (nlev + 1 < 258) ? nlev + 1 : 258;
  for (int i = tid; i < nl; i += 256) lst[i] = LSTART[i];
  __syncthreads();

  for (int L = 0; L < nlev; L++) {
    const int s0 = (L < 257) ? lst[L] : LSTART[L];
    const int s1 = (L + 1 < 258) ? lst[L + 1] : LSTART[L + 1];
    const int items = (s1 - s0) * 2;
    for (int it = tid; it < items; it += 256) {
      const int s = s0 + (it >> 1);
      const int ch = it & 1;
      const size_t goff = (size_t)(b * NSEQ + s) * DIN + (d8a + ch) * 8;
      union { uint4 u; unsigned short h[8]; } da, dbx, hpu, hvu;
      da.u = *(const uint4*)(DAp + goff);
      dbx.u = *(const uint4*)(DBXp + goff);
      const int pk = spack[s];
      const int node = pk & 4095;
      const int pn = (pk >> 12) - 1;
      float hp[8];
      if (pn >= 0) {
        hpu.u = *(const uint4*)(hl + pn * 16 + ch * 8);
#pragma unroll
        for (int e = 0; e < 8; e++) hp[e] = bf2f(hpu.h[e]);
      } else {
#pragma unroll
        for (int e = 0; e < 8; e++) hp[e] = 0.f;
      }
#pragma unroll
      for (int e = 0; e < 8; e++) {
        const float hv = fmaf(bf2f(da.h[e]), hp[e], bf2f(dbx.h[e]));
        hvu.h[e] = f2bf(hv);
      }
      *(uint4*)(hl + node * 16 + ch * 8) = hvu.u;
    }
    __syncthreads();
  }

  // flush h to global (node-major for ln)
  for (int i = tid; i < NSEQ * 2; i += 256) {
    const int node = i >> 1, ch = i & 1;
    *(uint4*)(Hb + (size_t)(b * NSEQ + node) * DIN + (d8a + ch) * 8) =
        *(const uint4*)(hl + node * 16 + ch * 8);
  }
}

// --------------------------------------------- y, layernorm, z-gate -> bf16
__global__ __launch_bounds__(256) void ln_kernel(
    const unsigned short* __restrict__ Hb, const float* __restrict__ CCv,
    const unsigned short* __restrict__ XI, const float* __restrict__ Dp,
    const float* __restrict__ gamma, const float* __restrict__ beta,
    const unsigned short* __restrict__ Z, unsigned short* __restrict__ YLN) {
  const int row = blockIdx.x;
  const int tid = threadIdx.x;
  const float C = CCv[row];
  const unsigned short* hrow = Hb + (size_t)row * DIN;
  const unsigned short* xrow = XI + (size_t)row * DIN;
  float y[6];
  float s = 0.f, s2 = 0.f;
#pragma unroll
  for (int i = 0; i < 6; i++) {
    const int d = tid + i * 256;
    const float v = fmaf(bf2f(hrow[d]), C, Dp[d] * bf2f(xrow[d]));
    y[i] = v;
    s += v;
    s2 = fmaf(v, v, s2);
  }
#pragma unroll
  for (int off = 32; off >= 1; off >>= 1) {
    s += __shfl_down(s, off);
    s2 += __shfl_down(s2, off);
  }
  __shared__ float rs[4], rs2[4];
  const int w = tid >> 6;
  if ((tid & 63) == 0) {
    rs[w] = s;
    rs2[w] = s2;
  }
  __syncthreads();
  const float ts = rs[0] + rs[1] + rs[2] + rs[3];
  const float ts2 = rs2[0] + rs2[1] + rs2[2] + rs2[3];
  const float mu = ts * (1.f / 1536.f);
  const float var = ts2 * (1.f / 1536.f) - mu * mu;
  const float inv = rsqrtf(var + 1e-5f);
  unsigned short* yrow = YLN + (size_t)row * DIN;
  const unsigned short* zrow = Z + (size_t)row * DIN;
#pragma unroll
  for (int i = 0; i < 6; i++) {
    const int d = tid + i * 256;
    const float o = (y[i] - mu) * inv * gamma[d] + beta[d];
    yrow[d] = f2bf(o * bf2f(zrow[d]));
  }
}

// ---------------------------------------------------------------------- launch
extern "C" void kernel_launch(void* const* d_in, const int* in_sizes, int n_in,
                              void* d_out, int out_size, void* d_ws, size_t ws_size,
                              hipStream_t stream) {
  const float* x = (const float*)d_in[0];
  const int* sidx = (const int*)d_in[1];
  const int* spar = (const int*)d_in[2];
  const float* in_proj = (const float*)d_in[3];
  const float* x_proj = (const float*)d_in[4];
  const float* dt_proj = (const float*)d_in[5];
  const float* dt_b = (const float*)d_in[6];
  const float* A_log = (const float*)d_in[7];
  const float* Dp = (const float*)d_in[8];
  const float* gamma = (const float*)d_in[9];
  const float* beta = (const float*)d_in[10];
  const float* out_proj = (const float*)d_in[11];
  float* out = (float*)d_out;

  char* p = (char*)d_ws;
  const size_t RC = (size_t)ROWS * DIN;
  unsigned short* XI = (unsigned short*)p;   p += RC * 2;   // 25.2 MB
  unsigned short* Z = (unsigned short*)p;    p += RC * 2;   // 25.2 MB
  unsigned short* DAp = (unsigned short*)p;  p += RC * 2;   // 25.2 MB
  unsigned short* DBXp = (unsigned short*)p; p += RC * 2;   // 25.2 MB
  unsigned short* Hb = (unsigned short*)p;   p += RC * 2;   // 25.2 MB
  float* XP = (float*)p;                     p += (size_t)NSPLIT * ROWS * 64 * 4;  // 16.8 MB
  unsigned short* DTLRb = (unsigned short*)p; p += (size_t)ROWS * 64 * 2;          // 1 MB
  float* BCv = (float*)p;                    p += ROWS * 4;
  float* CCv = (float*)p;                    p += ROWS * 4;
  float* negA = (float*)p;                   p += DIN * 4;
  unsigned short* Xbf = (unsigned short*)p;  p += (size_t)ROWS * DMOD * 2;         // 12.6 MB
  unsigned short* W1t = (unsigned short*)p;  p += (size_t)2 * DIN * DMOD * 2;      // 4.7 MB
  unsigned short* W2t = (unsigned short*)p;  p += (size_t)DMOD * DIN * 2;          // 2.4 MB
  unsigned short* XPW = (unsigned short*)p;  p += (size_t)64 * DIN * 2;
  unsigned short* DTWb = (unsigned short*)p; p += (size_t)DIN * 64 * 2;
  int* ipart = (int*)p;
  int* SLOT_PACK = ipart;
  int* SLOTINV = ipart + 2048;
  int* LSTART = ipart + 4096;
  int* NLEV = ipart + 4096 + 2049;
  unsigned short* YLN = DAp;  // DAp dead after recur; reuse for LN output

  prep1_kernel<<<1731, 1024, 0, stream>>>(sidx, spar, SLOT_PACK, SLOTINV,
                                          LSTART, NLEV, x, Xbf, x_proj, XPW,
                                          dt_proj, DTWb, A_log, negA);
  prep2_kernel<<<3456, 256, 0, stream>>>(in_proj, W1t, out_proj, W2t);
  mfma_gemm<1><<<dim3(24, 64), 256, 0, stream>>>(Xbf, W1t, XI, Z, DMOD, DIN);
  xdbl_mfma<<<dim3(NSPLIT, 64), 256, 0, stream>>>(XI, XPW, XP);
  xp_reduce<<<ROWS * 16 / 256, 256, 0, stream>>>(XP, DTLRb, BCv, CCv);
  dt_gemm<<<dim3(12, 128), 256, 0, stream>>>(DTLRb, DTWb, dt_b, negA, BCv, XI,
                                             SLOTINV, DAp, DBXp);
  recur_kernel<<<384, 256, 0, stream>>>(DAp, DBXp, Hb, SLOT_PACK, LSTART, NLEV);
  ln_kernel<<<ROWS, 256, 0, stream>>>(Hb, CCv, XI, Dp, gamma, beta, Z, YLN);
  mfma_gemm<0><<<dim3(6, 64), 256, 0, stream>>>(YLN, W2t, out, nullptr, DIN, DMOD);
}